// Round 1
// baseline (1118.897 us; speedup 1.0000x reference)
//
#include <hip/hip_runtime.h>
#include <hip/hip_bf16.h>

// Problem constants
#define BATCH 65536
#define DIM   256
#define CODES 1024

// Tiling
#define MT 32    // rows per block
#define NT 128   // codes per N-iteration
#define DK 32    // d-chunk staged in LDS per inner pass

// ---------------------------------------------------------------------------
// Kernel 1: per-code squared norms |e_k|^2 -> ws (1024 floats)
// ---------------------------------------------------------------------------
__global__ void vq_enorm_kernel(const float* __restrict__ E, float* __restrict__ enorm) {
    int k = blockIdx.x;          // 0..1023
    int lane = threadIdx.x;      // 0..63
    const float4 v = *(const float4*)(E + (size_t)k * DIM + lane * 4);
    float s = v.x * v.x + v.y * v.y + v.z * v.z + v.w * v.w;
    // wave-64 reduce
    s += __shfl_down(s, 32);
    s += __shfl_down(s, 16);
    s += __shfl_down(s, 8);
    s += __shfl_down(s, 4);
    s += __shfl_down(s, 2);
    s += __shfl_down(s, 1);
    if (lane == 0) enorm[k] = s;
}

// ---------------------------------------------------------------------------
// Kernel 2: fused distance + argmin + outputs
//   grid = BATCH/MT blocks of 256 threads
//   LDS: A-tile (32 rows x 256 d, padded stride 260) loaded once,
//        B-chunk (128 codes x 32 d, padded stride 36) streamed,
//        code norms (1024), per-row argmin result (32).
// ---------------------------------------------------------------------------
__global__ __launch_bounds__(256, 2) void vq_main_kernel(
    const float* __restrict__ X, const float* __restrict__ E,
    const float* __restrict__ enorm,
    float* __restrict__ loss, float* __restrict__ qst, float* __restrict__ onehot) {

    __shared__ float As[MT][DIM + 4];   // 32 x 260 floats = 33280 B
    __shared__ float Bs[NT][DK + 4];    // 128 x 36 floats = 18432 B
    __shared__ float Es[CODES];         // 4096 B
    __shared__ int   IdxS[MT];          // 128 B

    const int tid  = threadIdx.x;
    const int row0 = blockIdx.x * MT;

    // ---- load A tile (contiguous 32 KB) ----
    #pragma unroll
    for (int j = 0; j < 8; ++j) {
        int f = (j * 256 + tid) * 4;       // flat float index in tile
        int r = f >> 8;
        int d = f & 255;
        float4 v = *(const float4*)(X + (size_t)row0 * DIM + f);
        *(float4*)&As[r][d] = v;
    }
    // ---- load code norms ----
    #pragma unroll
    for (int j = 0; j < 4; ++j) Es[tid + j * 256] = enorm[tid + j * 256];

    const int tx = tid & 15;     // code split
    const int ty = tid >> 4;     // row split
    const int r0 = ty;
    const int r1 = ty + 16;

    float best0 = 3.4e38f, best1 = 3.4e38f;
    int   bidx0 = 0,       bidx1 = 0;

    __syncthreads();

    for (int nt = 0; nt < CODES; nt += NT) {
        float acc0[8], acc1[8];
        #pragma unroll
        for (int j = 0; j < 8; ++j) { acc0[j] = 0.f; acc1[j] = 0.f; }

        for (int dk = 0; dk < DIM; dk += DK) {
            // stage B chunk: codes [nt, nt+128), dims [dk, dk+32)
            {
                int cl = tid >> 3;            // 0..31
                int dl = (tid & 7) * 4;       // 0..28
                #pragma unroll
                for (int j = 0; j < 4; ++j) {
                    int c = cl + j * 32;
                    float4 v = *(const float4*)(E + (size_t)(nt + c) * DIM + dk + dl);
                    *(float4*)&Bs[c][dl] = v;
                }
            }
            __syncthreads();

            #pragma unroll
            for (int d = 0; d < DK; d += 4) {
                float4 a0 = *(float4*)&As[r0][dk + d];
                float4 a1 = *(float4*)&As[r1][dk + d];
                #pragma unroll
                for (int j = 0; j < 8; ++j) {
                    float4 b = *(float4*)&Bs[tx + 16 * j][d];
                    acc0[j] += a0.x * b.x + a0.y * b.y + a0.z * b.z + a0.w * b.w;
                    acc1[j] += a1.x * b.x + a1.y * b.y + a1.z * b.z + a1.w * b.w;
                }
            }
            __syncthreads();
        }

        // local argmin update (codes ascend within a thread -> strict < keeps
        // the lowest index on exact ties, matching jnp.argmin first-min)
        #pragma unroll
        for (int j = 0; j < 8; ++j) {
            int c = nt + tx + 16 * j;
            float d0 = Es[c] - 2.0f * acc0[j];
            float d1 = Es[c] - 2.0f * acc1[j];
            if (d0 < best0) { best0 = d0; bidx0 = c; }
            if (d1 < best1) { best1 = d1; bidx1 = c; }
        }
    }

    // reduce across the 16 tx-lanes sharing each row (same wave, low 4 lane bits)
    #pragma unroll
    for (int m = 1; m < 16; m <<= 1) {
        float od0 = __shfl_xor(best0, m);
        int   oi0 = __shfl_xor(bidx0, m);
        if (od0 < best0 || (od0 == best0 && oi0 < bidx0)) { best0 = od0; bidx0 = oi0; }
        float od1 = __shfl_xor(best1, m);
        int   oi1 = __shfl_xor(bidx1, m);
        if (od1 < best1 || (od1 == best1 && oi1 < bidx1)) { best1 = od1; bidx1 = oi1; }
    }
    if (tx == 0) { IdxS[r0] = bidx0; IdxS[r1] = bidx1; }
    __syncthreads();

    // ---- fused epilogue: loss + quantized_st for the 32 rows ----
    #pragma unroll
    for (int j = 0; j < 8; ++j) {
        int f = (j * 256 + tid) * 4;
        int r = f >> 8;
        int d = f & 255;
        float4 x = *(float4*)&As[r][d];
        float4 q = *(const float4*)(E + (size_t)IdxS[r] * DIM + d);
        float4 dl, lo, qs;
        dl.x = q.x - x.x; dl.y = q.y - x.y; dl.z = q.z - x.z; dl.w = q.w - x.w;
        lo.x = 0.25f * dl.x * dl.x; lo.y = 0.25f * dl.y * dl.y;
        lo.z = 0.25f * dl.z * dl.z; lo.w = 0.25f * dl.w * dl.w;
        qs.x = x.x + dl.x; qs.y = x.y + dl.y; qs.z = x.z + dl.z; qs.w = x.w + dl.w;
        size_t o = (size_t)row0 * DIM + f;
        *(float4*)(loss + o) = lo;
        *(float4*)(qst + o)  = qs;
    }

    // ---- one-hot ones (zeros handled by memset before this kernel) ----
    if (tid < MT) {
        onehot[(size_t)(row0 + tid) * CODES + IdxS[tid]] = 1.0f;
    }
}

extern "C" void kernel_launch(void* const* d_in, const int* in_sizes, int n_in,
                              void* d_out, int out_size, void* d_ws, size_t ws_size,
                              hipStream_t stream) {
    const float* X = (const float*)d_in[0];   // (65536, 256)
    const float* E = (const float*)d_in[1];   // (1024, 256)
    float* out = (float*)d_out;

    float* loss   = out;                                  // 16777216
    float* qst    = out + (size_t)BATCH * DIM;            // 16777216
    float* onehot = out + (size_t)2 * BATCH * DIM;        // 67108864

    float* enorm = (float*)d_ws;                          // 1024 floats

    // zero the one-hot region (256 MB); ones are scattered by the main kernel
    hipMemsetAsync(onehot, 0, (size_t)BATCH * CODES * sizeof(float), stream);

    vq_enorm_kernel<<<CODES, 64, 0, stream>>>(E, enorm);

    vq_main_kernel<<<BATCH / MT, 256, 0, stream>>>(X, E, enorm, loss, qst, onehot);
}

// Round 2
// 844.642 us; speedup vs baseline: 1.3247x; 1.3247x over previous
//
#include <hip/hip_runtime.h>

#define BATCH 65536
#define DIM   256
#define CODES 1024
#define TAU   0.02f

typedef short bf16x8 __attribute__((ext_vector_type(8)));
typedef float f32x4  __attribute__((ext_vector_type(4)));

__device__ inline unsigned short f2bf(float f) {
    unsigned u = __float_as_uint(f);
    u += 0x7FFFu + ((u >> 16) & 1u);
    return (unsigned short)(u >> 16);
}
__device__ inline float bf2f(unsigned short h) {
    return __uint_as_float(((unsigned)h) << 16);
}

// ---------------------------------------------------------------------------
// Prep: E -> E_hi/E_lo (bf16 split) + |e|^2 per code
// ---------------------------------------------------------------------------
__global__ void vq_prep(const float* __restrict__ E, float* __restrict__ enorm,
                        unsigned short* __restrict__ Ehi, unsigned short* __restrict__ Elo) {
    int k = blockIdx.x;      // code
    int lane = threadIdx.x;  // 0..63
    const float4 v = *(const float4*)(E + (size_t)k * DIM + lane * 4);
    float s = v.x * v.x + v.y * v.y + v.z * v.z + v.w * v.w;
    float f[4] = {v.x, v.y, v.z, v.w};
    ushort4 hv, lv;
    unsigned short h;
    h = f2bf(f[0]); hv.x = h; lv.x = f2bf(f[0] - bf2f(h));
    h = f2bf(f[1]); hv.y = h; lv.y = f2bf(f[1] - bf2f(h));
    h = f2bf(f[2]); hv.z = h; lv.z = f2bf(f[2] - bf2f(h));
    h = f2bf(f[3]); hv.w = h; lv.w = f2bf(f[3] - bf2f(h));
    *(ushort4*)(Ehi + (size_t)k * DIM + lane * 4) = hv;
    *(ushort4*)(Elo + (size_t)k * DIM + lane * 4) = lv;
    s += __shfl_down(s, 32);
    s += __shfl_down(s, 16);
    s += __shfl_down(s, 8);
    s += __shfl_down(s, 4);
    s += __shfl_down(s, 2);
    s += __shfl_down(s, 1);
    if (lane == 0) enorm[k] = s;
}

// ---------------------------------------------------------------------------
// Main: MFMA distances + per-row argmin (best + second-best margin)
//   block = 256 thr (4 waves), 128 rows/block (32 rows/wave), grid = 512
//   A-fragments (X rows, bf16 hi/lo) in registers; E tiles (16 codes x 256 k,
//   hi+lo) double-buffered in LDS in MFMA fragment order.
// ---------------------------------------------------------------------------
__global__ __launch_bounds__(256, 2) void vq_main(
    const float* __restrict__ X,
    const unsigned short* __restrict__ Ehi, const unsigned short* __restrict__ Elo,
    const float* __restrict__ enorm,
    int* __restrict__ rowidx, int* __restrict__ cnt, int* __restrict__ list) {

    // per buffer: hi 8 ksteps x 64 lanes x 8 bf16 = 4096 ushort, lo same
    __shared__ unsigned short Eb[2][8192];   // 32768 B
    __shared__ float EsL[CODES];             // 4096 B

    const int tid  = threadIdx.x;
    const int lane = tid & 63;
    const int w    = tid >> 6;               // wave 0..3
    const int m    = lane & 15;              // row-in-16 (A) / code col (B,C)
    const int quad = lane >> 4;              // 0..3
    const int row0 = blockIdx.x * 128 + w * 32;

    for (int i = tid; i < CODES; i += 256) EsL[i] = enorm[i];

    // ---- A fragments: 2 row-groups x 8 ksteps, hi+lo (128 VGPRs) ----
    bf16x8 ahi[2][8], alo[2][8];
    #pragma unroll
    for (int g = 0; g < 2; ++g) {
        const float* xr = X + (size_t)(row0 + g * 16 + m) * DIM + quad * 8;
        #pragma unroll
        for (int s = 0; s < 8; ++s) {
            float4 p0 = *(const float4*)(xr + s * 32);
            float4 p1 = *(const float4*)(xr + s * 32 + 4);
            float f[8] = {p0.x, p0.y, p0.z, p0.w, p1.x, p1.y, p1.z, p1.w};
            #pragma unroll
            for (int j = 0; j < 8; ++j) {
                unsigned short h = f2bf(f[j]);
                ahi[g][s][j] = (short)h;
                alo[g][s][j] = (short)f2bf(f[j] - bf2f(h));
            }
        }
    }

    // staging: thread covers hi slots (s=w, l=lane), (s=4+w, l=lane); same lo.
    // slot (s,l) holds E_*[tile*16 + (l&15)][s*32 + (l>>4)*8 .. +8]
    bf16x8 ra, rb, rc, rd;
    {
        const unsigned short* sh = Ehi + (size_t)m * DIM + w * 32 + quad * 8;
        const unsigned short* sl = Elo + (size_t)m * DIM + w * 32 + quad * 8;
        ra = *(const bf16x8*)sh;  rb = *(const bf16x8*)(sh + 128);
        rc = *(const bf16x8*)sl;  rd = *(const bf16x8*)(sl + 128);
    }
    {
        unsigned short* b = &Eb[0][0];
        *(bf16x8*)(b + (w * 512 + lane * 8))              = ra;
        *(bf16x8*)(b + ((4 + w) * 512 + lane * 8))        = rb;
        *(bf16x8*)(b + (4096 + w * 512 + lane * 8))       = rc;
        *(bf16x8*)(b + (4096 + (4 + w) * 512 + lane * 8)) = rd;
    }
    __syncthreads();

    float best[8], sec[8];
    int   bidx[8];
    #pragma unroll
    for (int i = 0; i < 8; ++i) { best[i] = 3.4e38f; sec[i] = 3.4e38f; bidx[i] = 0; }

    for (int t = 0; t < 64; ++t) {
        const int buf = t & 1;
        if (t < 63) {   // prefetch next tile into registers (loads in flight during MFMA)
            const size_t rbase = (size_t)((t + 1) * 16 + m) * DIM + w * 32 + quad * 8;
            ra = *(const bf16x8*)(Ehi + rbase);  rb = *(const bf16x8*)(Ehi + rbase + 128);
            rc = *(const bf16x8*)(Elo + rbase);  rd = *(const bf16x8*)(Elo + rbase + 128);
        }
        f32x4 acc0 = {0.f, 0.f, 0.f, 0.f}, acc1 = {0.f, 0.f, 0.f, 0.f};
        const unsigned short* b = &Eb[buf][0];
        #pragma unroll
        for (int s = 0; s < 8; ++s) {
            bf16x8 bh = *(const bf16x8*)(b + s * 512 + lane * 8);
            bf16x8 bl = *(const bf16x8*)(b + 4096 + s * 512 + lane * 8);
            acc0 = __builtin_amdgcn_mfma_f32_16x16x32_bf16(ahi[0][s], bh, acc0, 0, 0, 0);
            acc1 = __builtin_amdgcn_mfma_f32_16x16x32_bf16(ahi[1][s], bh, acc1, 0, 0, 0);
            acc0 = __builtin_amdgcn_mfma_f32_16x16x32_bf16(alo[0][s], bh, acc0, 0, 0, 0);
            acc1 = __builtin_amdgcn_mfma_f32_16x16x32_bf16(alo[1][s], bh, acc1, 0, 0, 0);
            acc0 = __builtin_amdgcn_mfma_f32_16x16x32_bf16(ahi[0][s], bl, acc0, 0, 0, 0);
            acc1 = __builtin_amdgcn_mfma_f32_16x16x32_bf16(ahi[1][s], bl, acc1, 0, 0, 0);
        }
        // C layout: col = lane&15 (code), row = quad*4 + reg
        const float es = EsL[t * 16 + m];
        const int   c  = t * 16 + m;
        #pragma unroll
        for (int g = 0; g < 2; ++g) {
            #pragma unroll
            for (int r = 0; r < 4; ++r) {
                float d = es - 2.0f * (g ? acc1[r] : acc0[r]);
                int i = g * 4 + r;
                if (d < best[i]) { sec[i] = best[i]; best[i] = d; bidx[i] = c; }
                else if (d < sec[i]) sec[i] = d;
            }
        }
        if (t < 63) {
            unsigned short* bn = &Eb[buf ^ 1][0];
            *(bf16x8*)(bn + (w * 512 + lane * 8))              = ra;
            *(bf16x8*)(bn + ((4 + w) * 512 + lane * 8))        = rb;
            *(bf16x8*)(bn + (4096 + w * 512 + lane * 8))       = rc;
            *(bf16x8*)(bn + (4096 + (4 + w) * 512 + lane * 8)) = rd;
        }
        __syncthreads();
    }

    // cross-lane argmin reduce over the 16 code-columns (low 4 lane bits)
    #pragma unroll
    for (int i = 0; i < 8; ++i) {
        float b0 = best[i], s0 = sec[i];
        int   i0 = bidx[i];
        #pragma unroll
        for (int msk = 1; msk < 16; msk <<= 1) {
            float ob = __shfl_xor(b0, msk);
            float os = __shfl_xor(s0, msk);
            int   oi = __shfl_xor(i0, msk);
            if (ob < b0 || (ob == b0 && oi < i0)) {
                s0 = fminf(b0, os);
                b0 = ob; i0 = oi;
            } else {
                s0 = fminf(s0, ob);
            }
        }
        best[i] = b0; sec[i] = s0; bidx[i] = i0;
    }
    if (m == 0) {
        #pragma unroll
        for (int i = 0; i < 8; ++i) {
            int g = i >> 2, r = i & 3;
            int grow = row0 + g * 16 + quad * 4 + r;
            rowidx[grow] = bidx[i];
            if (sec[i] - best[i] < TAU) {          // near-tie: exact recheck
                int p = atomicAdd(cnt, 1);
                if (p < BATCH) list[p] = grow;
            }
        }
    }
}

// ---------------------------------------------------------------------------
// Repair: exact fp32 argmin for flagged rows (expected ~100 rows)
// ---------------------------------------------------------------------------
__global__ void vq_repair(const float* __restrict__ X, const float* __restrict__ E,
                          const float* __restrict__ enorm,
                          int* __restrict__ rowidx, const int* __restrict__ cnt,
                          const int* __restrict__ list) {
    __shared__ float xs[DIM];
    __shared__ float rbest[256];
    __shared__ int   ridx[256];
    int n = *cnt; if (n > BATCH) n = BATCH;
    for (int i = blockIdx.x; i < n; i += gridDim.x) {
        const int row = list[i];
        if (threadIdx.x < 64) {
            float4 v = *(const float4*)(X + (size_t)row * DIM + threadIdx.x * 4);
            *(float4*)(xs + threadIdx.x * 4) = v;
        }
        __syncthreads();
        float bb = 3.4e38f; int bi = 0;
        for (int cc = 0; cc < 4; ++cc) {
            const int c = threadIdx.x + cc * 256;
            const float* er = E + (size_t)c * DIM;
            float dx = 0.f, dy = 0.f, dz = 0.f, dw = 0.f;
            for (int k = 0; k < DIM; k += 4) {
                float4 e4 = *(const float4*)(er + k);
                dx += xs[k] * e4.x; dy += xs[k + 1] * e4.y;
                dz += xs[k + 2] * e4.z; dw += xs[k + 3] * e4.w;
            }
            float d = enorm[c] - 2.0f * ((dx + dy) + (dz + dw));
            if (d < bb) { bb = d; bi = c; }   // c ascending -> first-min kept
        }
        rbest[threadIdx.x] = bb; ridx[threadIdx.x] = bi;
        __syncthreads();
        for (int off = 128; off > 0; off >>= 1) {
            if (threadIdx.x < off) {
                float ob = rbest[threadIdx.x + off]; int oi = ridx[threadIdx.x + off];
                if (ob < rbest[threadIdx.x] ||
                    (ob == rbest[threadIdx.x] && oi < ridx[threadIdx.x])) {
                    rbest[threadIdx.x] = ob; ridx[threadIdx.x] = oi;
                }
            }
            __syncthreads();
        }
        if (threadIdx.x == 0) rowidx[row] = ridx[0];
        __syncthreads();
    }
}

// ---------------------------------------------------------------------------
// Epilogue: loss, quantized_st, one-hot scatter (bitwise-identical elementwise
// ops to the reference; indices final after repair)
// ---------------------------------------------------------------------------
__global__ __launch_bounds__(256) void vq_epilogue(
    const float* __restrict__ X, const float* __restrict__ E,
    const int* __restrict__ rowidx,
    float* __restrict__ loss, float* __restrict__ qst, float* __restrict__ onehot) {
    const size_t gid  = (size_t)blockIdx.x * 256 + threadIdx.x;
    const size_t base = gid * 4;
    const int row = (int)(base >> 8);
    const int col = (int)(base & 255);
    const int idx = rowidx[row];
    float4 x = *(const float4*)(X + base);
    float4 q = *(const float4*)(E + (size_t)idx * DIM + col);
    float4 dl = {q.x - x.x, q.y - x.y, q.z - x.z, q.w - x.w};
    float4 lo = {0.25f * dl.x * dl.x, 0.25f * dl.y * dl.y,
                 0.25f * dl.z * dl.z, 0.25f * dl.w * dl.w};
    float4 qs = {x.x + dl.x, x.y + dl.y, x.z + dl.z, x.w + dl.w};
    *(float4*)(loss + base) = lo;
    *(float4*)(qst + base)  = qs;
    if (col == 0) onehot[(size_t)row * CODES + idx] = 1.0f;
}

extern "C" void kernel_launch(void* const* d_in, const int* in_sizes, int n_in,
                              void* d_out, int out_size, void* d_ws, size_t ws_size,
                              hipStream_t stream) {
    const float* X = (const float*)d_in[0];   // (65536, 256)
    const float* E = (const float*)d_in[1];   // (1024, 256)
    float* out = (float*)d_out;
    float* loss   = out;
    float* qst    = out + (size_t)BATCH * DIM;
    float* onehot = out + (size_t)2 * BATCH * DIM;

    char* ws = (char*)d_ws;
    float*          enorm  = (float*)ws;                        // 4 KB
    unsigned short* Ehi    = (unsigned short*)(ws + 4096);      // 512 KB
    unsigned short* Elo    = (unsigned short*)(ws + 528384);    // 512 KB
    int*            rowidx = (int*)(ws + 1052672);              // 256 KB
    int*            cnt    = (int*)(ws + 1314816);              // 4 B
    int*            list   = (int*)(ws + 1314880);              // 256 KB

    hipMemsetAsync(onehot, 0, (size_t)BATCH * CODES * sizeof(float), stream);
    hipMemsetAsync(cnt, 0, sizeof(int), stream);

    vq_prep<<<CODES, 64, 0, stream>>>(E, enorm, Ehi, Elo);
    vq_main<<<BATCH / 128, 256, 0, stream>>>(X, Ehi, Elo, enorm, rowidx, cnt, list);
    vq_repair<<<128, 256, 0, stream>>>(X, E, enorm, rowidx, cnt, list);
    vq_epilogue<<<(BATCH * DIM / 4) / 256, 256, 0, stream>>>(X, E, rowidx, loss, qst, onehot);
}

// Round 4
// 622.299 us; speedup vs baseline: 1.7980x; 1.3573x over previous
//
#include <hip/hip_runtime.h>

#define BATCH 65536
#define DIM   256
#define CODES 1024
#define TAU   6e-3f

typedef short bf16x8 __attribute__((ext_vector_type(8)));
typedef float f32x4  __attribute__((ext_vector_type(4)));

__device__ inline unsigned short f2bf(float f) {
    unsigned u = __float_as_uint(f);
    u += 0x7FFFu + ((u >> 16) & 1u);
    return (unsigned short)(u >> 16);
}
__device__ inline float bf2f(unsigned short h) {
    return __uint_as_float(((unsigned)h) << 16);
}

// async global->LDS, 16B per lane; LDS dest = uniform base + lane*16
#define GLL(gptr, lptr) \
    __builtin_amdgcn_global_load_lds( \
        (const __attribute__((address_space(1))) void*)(gptr), \
        (__attribute__((address_space(3))) void*)(lptr), 16, 0, 0)

// ---------------------------------------------------------------------------
// Prep: E -> E_hi/E_lo (bf16 split) + |e|^2 per code
// ---------------------------------------------------------------------------
__global__ void vq_prep(const float* __restrict__ E, float* __restrict__ enorm,
                        unsigned short* __restrict__ Ehi, unsigned short* __restrict__ Elo) {
    int k = blockIdx.x;      // code
    int lane = threadIdx.x;  // 0..63
    const float4 v = *(const float4*)(E + (size_t)k * DIM + lane * 4);
    float s = v.x * v.x + v.y * v.y + v.z * v.z + v.w * v.w;
    float f[4] = {v.x, v.y, v.z, v.w};
    ushort4 hv, lv;
    unsigned short h;
    h = f2bf(f[0]); hv.x = h; lv.x = f2bf(f[0] - bf2f(h));
    h = f2bf(f[1]); hv.y = h; lv.y = f2bf(f[1] - bf2f(h));
    h = f2bf(f[2]); hv.z = h; lv.z = f2bf(f[2] - bf2f(h));
    h = f2bf(f[3]); hv.w = h; lv.w = f2bf(f[3] - bf2f(h));
    *(ushort4*)(Ehi + (size_t)k * DIM + lane * 4) = hv;
    *(ushort4*)(Elo + (size_t)k * DIM + lane * 4) = lv;
    s += __shfl_down(s, 32);
    s += __shfl_down(s, 16);
    s += __shfl_down(s, 8);
    s += __shfl_down(s, 4);
    s += __shfl_down(s, 2);
    s += __shfl_down(s, 1);
    if (lane == 0) enorm[k] = s;
}

// ---------------------------------------------------------------------------
// Main: MFMA distances + per-row argmin (best + second-best margin)
//   block = 256 thr (4 waves), 128 rows/block, grid = 512
//   E tiles (16 codes x 256 k, hi+lo) double-buffered in LDS via
//   global_load_lds (LDS slot layout is exactly uniform_base + lane*16).
// ---------------------------------------------------------------------------
__global__ __launch_bounds__(256, 2) void vq_main(
    const float* __restrict__ X,
    const unsigned short* __restrict__ Ehi, const unsigned short* __restrict__ Elo,
    const float* __restrict__ enorm,
    int* __restrict__ rowidx, int* __restrict__ cnt, int* __restrict__ list) {

    // per buffer: hi 8 ksteps x 64 lanes x 8 bf16 = 4096 ushort, lo same
    __shared__ unsigned short Eb[2][8192];   // 32768 B
    __shared__ float EsL[CODES];             // 4096 B

    const int tid  = threadIdx.x;
    const int lane = tid & 63;
    const int w    = tid >> 6;               // wave 0..3
    const int m    = lane & 15;              // row-in-16 (A) / code col (B,C)
    const int quad = lane >> 4;              // 0..3
    const int row0 = blockIdx.x * 128 + w * 32;

    // prologue: async-stage tile 0 into buf 0 (in flight during A-frag build)
    {
        const size_t rb0 = (size_t)m * DIM + w * 32 + quad * 8;
        GLL(Ehi + rb0,       &Eb[0][w * 512]);
        GLL(Ehi + rb0 + 128, &Eb[0][(4 + w) * 512]);
        GLL(Elo + rb0,       &Eb[0][4096 + w * 512]);
        GLL(Elo + rb0 + 128, &Eb[0][4096 + (4 + w) * 512]);
    }

    for (int i = tid; i < CODES; i += 256) EsL[i] = enorm[i];

    // ---- A fragments: 2 row-groups x 8 ksteps, hi+lo (128 VGPRs) ----
    bf16x8 ahi[2][8], alo[2][8];
    #pragma unroll
    for (int g = 0; g < 2; ++g) {
        const float* xr = X + (size_t)(row0 + g * 16 + m) * DIM + quad * 8;
        #pragma unroll
        for (int s = 0; s < 8; ++s) {
            float4 p0 = *(const float4*)(xr + s * 32);
            float4 p1 = *(const float4*)(xr + s * 32 + 4);
            float f[8] = {p0.x, p0.y, p0.z, p0.w, p1.x, p1.y, p1.z, p1.w};
            #pragma unroll
            for (int j = 0; j < 8; ++j) {
                unsigned short h = f2bf(f[j]);
                ahi[g][s][j] = (short)h;
                alo[g][s][j] = (short)f2bf(f[j] - bf2f(h));
            }
        }
    }

    __syncthreads();   // drains gll (vmcnt0) + EsL writes

    float best[8], sec[8];
    int   bidx[8];
    #pragma unroll
    for (int i = 0; i < 8; ++i) { best[i] = 3.4e38f; sec[i] = 3.4e38f; bidx[i] = 0; }

    for (int t = 0; t < 64; ++t) {
        const int buf = t & 1;
        if (t < 63) {   // async prefetch next tile into other buffer
            const size_t rbn = (size_t)((t + 1) * 16 + m) * DIM + w * 32 + quad * 8;
            unsigned short* bn = &Eb[buf ^ 1][0];
            GLL(Ehi + rbn,       bn + w * 512);
            GLL(Ehi + rbn + 128, bn + (4 + w) * 512);
            GLL(Elo + rbn,       bn + 4096 + w * 512);
            GLL(Elo + rbn + 128, bn + 4096 + (4 + w) * 512);
        }
        f32x4 acc0 = {0.f, 0.f, 0.f, 0.f}, acc1 = {0.f, 0.f, 0.f, 0.f};
        const unsigned short* b = &Eb[buf][0];
        #pragma unroll
        for (int s = 0; s < 8; ++s) {
            bf16x8 bh = *(const bf16x8*)(b + s * 512 + lane * 8);
            bf16x8 bl = *(const bf16x8*)(b + 4096 + s * 512 + lane * 8);
            acc0 = __builtin_amdgcn_mfma_f32_16x16x32_bf16(ahi[0][s], bh, acc0, 0, 0, 0);
            acc1 = __builtin_amdgcn_mfma_f32_16x16x32_bf16(ahi[1][s], bh, acc1, 0, 0, 0);
            acc0 = __builtin_amdgcn_mfma_f32_16x16x32_bf16(alo[0][s], bh, acc0, 0, 0, 0);
            acc1 = __builtin_amdgcn_mfma_f32_16x16x32_bf16(alo[1][s], bh, acc1, 0, 0, 0);
            acc0 = __builtin_amdgcn_mfma_f32_16x16x32_bf16(ahi[0][s], bl, acc0, 0, 0, 0);
            acc1 = __builtin_amdgcn_mfma_f32_16x16x32_bf16(ahi[1][s], bl, acc1, 0, 0, 0);
        }
        // C layout: col = lane&15 (code), row = quad*4 + reg
        const float es = EsL[t * 16 + m];
        const int   c  = t * 16 + m;
        #pragma unroll
        for (int g = 0; g < 2; ++g) {
            #pragma unroll
            for (int r = 0; r < 4; ++r) {
                float d = es - 2.0f * (g ? acc1[r] : acc0[r]);
                int i = g * 4 + r;
                if (d < best[i]) { sec[i] = best[i]; best[i] = d; bidx[i] = c; }
                else if (d < sec[i]) sec[i] = d;
            }
        }
        __syncthreads();   // drains prefetch + protects buf^1 reuse
    }

    // cross-lane argmin reduce over the 16 code-columns (low 4 lane bits)
    #pragma unroll
    for (int i = 0; i < 8; ++i) {
        float b0 = best[i], s0 = sec[i];
        int   i0 = bidx[i];
        #pragma unroll
        for (int msk = 1; msk < 16; msk <<= 1) {
            float ob = __shfl_xor(b0, msk);
            float os = __shfl_xor(s0, msk);
            int   oi = __shfl_xor(i0, msk);
            if (ob < b0 || (ob == b0 && oi < i0)) {
                s0 = fminf(b0, os);
                b0 = ob; i0 = oi;
            } else {
                s0 = fminf(s0, ob);
            }
        }
        best[i] = b0; sec[i] = s0; bidx[i] = i0;
    }
    if (m == 0) {
        #pragma unroll
        for (int i = 0; i < 8; ++i) {
            int g = i >> 2, r = i & 3;
            int grow = row0 + g * 16 + quad * 4 + r;
            rowidx[grow] = bidx[i];
            if (sec[i] - best[i] < TAU) {          // near-tie: exact recheck
                int p = atomicAdd(cnt, 1);
                if (p < BATCH) list[p] = grow;
            }
        }
    }
}

// ---------------------------------------------------------------------------
// Repair v2: exact fp32 argmin for flagged rows.
//   Lanes along k: 64 lanes x float4 = one coalesced code row; butterfly
//   reduce; 4 codes in flight; wave w owns codes [256w, 256w+256).
// ---------------------------------------------------------------------------
__global__ __launch_bounds__(256) void vq_repair(
    const float* __restrict__ X, const float* __restrict__ E,
    const float* __restrict__ enorm,
    int* __restrict__ rowidx, const int* __restrict__ cnt,
    const int* __restrict__ list) {
    __shared__ float wb[4];
    __shared__ int   wi[4];
    int n = *cnt; if (n > BATCH) n = BATCH;
    const int lane = threadIdx.x & 63;
    const int w    = threadIdx.x >> 6;
    for (int i = blockIdx.x; i < n; i += gridDim.x) {
        const int row = list[i];
        const float4 xv = *(const float4*)(X + (size_t)row * DIM + lane * 4);
        float bb = 3.4e38f; int bi = 0;
        for (int j = 0; j < 256; j += 4) {
            const int c = w * 256 + j;
            const float* e0 = E + (size_t)c * DIM + lane * 4;
            float4 v0 = *(const float4*)(e0);
            float4 v1 = *(const float4*)(e0 + DIM);
            float4 v2 = *(const float4*)(e0 + 2 * DIM);
            float4 v3 = *(const float4*)(e0 + 3 * DIM);
            float s0 = xv.x * v0.x + xv.y * v0.y + xv.z * v0.z + xv.w * v0.w;
            float s1 = xv.x * v1.x + xv.y * v1.y + xv.z * v1.z + xv.w * v1.w;
            float s2 = xv.x * v2.x + xv.y * v2.y + xv.z * v2.z + xv.w * v2.w;
            float s3 = xv.x * v3.x + xv.y * v3.y + xv.z * v3.z + xv.w * v3.w;
            #pragma unroll
            for (int msk = 32; msk >= 1; msk >>= 1) {
                s0 += __shfl_xor(s0, msk);
                s1 += __shfl_xor(s1, msk);
                s2 += __shfl_xor(s2, msk);
                s3 += __shfl_xor(s3, msk);
            }
            float d0 = enorm[c]     - 2.0f * s0;
            float d1 = enorm[c + 1] - 2.0f * s1;
            float d2 = enorm[c + 2] - 2.0f * s2;
            float d3 = enorm[c + 3] - 2.0f * s3;
            // c ascending within wave -> strict < keeps lowest index
            if (d0 < bb) { bb = d0; bi = c; }
            if (d1 < bb) { bb = d1; bi = c + 1; }
            if (d2 < bb) { bb = d2; bi = c + 2; }
            if (d3 < bb) { bb = d3; bi = c + 3; }
        }
        if (lane == 0) { wb[w] = bb; wi[w] = bi; }
        __syncthreads();
        if (threadIdx.x == 0) {
            float fb = wb[0]; int fi = wi[0];
            #pragma unroll
            for (int k = 1; k < 4; ++k)
                if (wb[k] < fb || (wb[k] == fb && wi[k] < fi)) { fb = wb[k]; fi = wi[k]; }
            rowidx[row] = fi;
        }
        __syncthreads();
    }
}

// ---------------------------------------------------------------------------
// Epilogue: loss, quantized_st, FULL one-hot rows (zero-fill fused, no memset)
//   1 wave per row; grid = BATCH/4 blocks of 256.
// ---------------------------------------------------------------------------
__global__ __launch_bounds__(256) void vq_epilogue(
    const float* __restrict__ X, const float* __restrict__ E,
    const int* __restrict__ rowidx,
    float* __restrict__ loss, float* __restrict__ qst, float* __restrict__ onehot) {
    const int lane = threadIdx.x & 63;
    const int w    = threadIdx.x >> 6;
    const int row  = blockIdx.x * 4 + w;
    const int idx  = rowidx[row];
    const size_t xb = (size_t)row * DIM + lane * 4;
    float4 x = *(const float4*)(X + xb);
    float4 q = *(const float4*)(E + (size_t)idx * DIM + lane * 4);
    float4 dl = {q.x - x.x, q.y - x.y, q.z - x.z, q.w - x.w};
    float4 lo = {0.25f * dl.x * dl.x, 0.25f * dl.y * dl.y,
                 0.25f * dl.z * dl.z, 0.25f * dl.w * dl.w};
    float4 qs = {x.x + dl.x, x.y + dl.y, x.z + dl.z, x.w + dl.w};
    *(float4*)(loss + xb) = lo;
    *(float4*)(qst + xb)  = qs;
    // one-hot: 4 ext-vector nontemporal stores per lane cover the 1024 row
    const size_t ob  = (size_t)row * CODES;
    const int slot = idx >> 2, r3 = idx & 3;
    #pragma unroll
    for (int j = 0; j < 4; ++j) {
        f32x4 z = {0.f, 0.f, 0.f, 0.f};
        if (slot == j * 64 + lane) z[r3] = 1.0f;
        __builtin_nontemporal_store(z, (f32x4*)(onehot + ob + j * 256 + lane * 4));
    }
}

extern "C" void kernel_launch(void* const* d_in, const int* in_sizes, int n_in,
                              void* d_out, int out_size, void* d_ws, size_t ws_size,
                              hipStream_t stream) {
    const float* X = (const float*)d_in[0];   // (65536, 256)
    const float* E = (const float*)d_in[1];   // (1024, 256)
    float* out = (float*)d_out;
    float* loss   = out;
    float* qst    = out + (size_t)BATCH * DIM;
    float* onehot = out + (size_t)2 * BATCH * DIM;

    char* ws = (char*)d_ws;
    float*          enorm  = (float*)ws;                        // 4 KB
    unsigned short* Ehi    = (unsigned short*)(ws + 4096);      // 512 KB
    unsigned short* Elo    = (unsigned short*)(ws + 528384);    // 512 KB
    int*            rowidx = (int*)(ws + 1052672);              // 256 KB
    int*            cnt    = (int*)(ws + 1314816);              // 4 B
    int*            list   = (int*)(ws + 1314880);              // 256 KB

    (void)hipMemsetAsync(cnt, 0, sizeof(int), stream);

    vq_prep<<<CODES, 64, 0, stream>>>(E, enorm, Ehi, Elo);
    vq_main<<<BATCH / 128, 256, 0, stream>>>(X, Ehi, Elo, enorm, rowidx, cnt, list);
    vq_repair<<<2048, 256, 0, stream>>>(X, E, enorm, rowidx, cnt, list);
    vq_epilogue<<<BATCH / 4, 256, 0, stream>>>(X, E, rowidx, loss, qst, onehot);
}